// Round 3
// baseline (52.615 us; speedup 1.0000x reference)
//
#include <hip/hip_runtime.h>
#include <hip/hip_bf16.h>
#include <hip/hip_cooperative_groups.h>

namespace cg = cooperative_groups;

// Problem constants (fixed by the reference module)
constexpr int B  = 8;
constexpr int LS = 256;            // L_SRC == L_TGT
constexpr int L  = 512;            // L_SRC + L_TGT
constexpr int H  = 768;
constexpr int S  = 128;            // N_SRC_WORDS
constexpr int NW = 256;            // S + T (pooled words used)

// ---------------------------------------------------------------------------
// Single cooperative kernel. 64 blocks x 1024 threads; block g=(b,s) owns the
// 64 tokens [s*64, s*64+64) of batch b.
//   phase 1: wave 0 does the batch's run-segmentation scan (redundant per
//            block, L2-hot); all 16 waves compute both dots per token.
//   phase 2: LDS partial per-segment sums -> psum[g][256] (fully overwritten,
//            so no zeroing pass and no stale state across graph replays).
//   grid.sync()
//   phase 3: reduce 8 partials per batch, divide by counts, write the 16-row
//            slice of the 128x128 broadcast-sum logits.
// ---------------------------------------------------------------------------
__global__ __launch_bounds__(1024) void fused_kernel(
    const float* __restrict__ tok, const int* __restrict__ mask,
    const int* __restrict__ sw, const int* __restrict__ tw,
    const float* __restrict__ Wp, const float* __restrict__ bias,
    float* __restrict__ out, float* __restrict__ psum)
{
    const int g    = blockIdx.x;        // 0..63
    const int b    = g >> 3;
    const int s    = g & 7;
    const int tid  = threadIdx.x;
    const int lane = tid & 63;
    const int wv   = tid >> 6;          // 0..15

    __shared__ int    sseg[L];
    __shared__ float2 dv[64];
    __shared__ float  part[NW + 1];
    __shared__ float  cnt[NW + 1];
    __shared__ float  pooled[NW];

    if (tid < NW + 1) { part[tid] = 0.f; cnt[tid] = 0.f; }
    __syncthreads();

    if (wv == 0) {
        // --- run-segmentation scan over all 512 tokens of batch b ---
        const int base = lane * 8;
        int wid[8]; bool val[8];
        #pragma unroll
        for (int j = 0; j < 8; ++j) {
            const int l = base + j;
            const int w = (l < LS) ? sw[b * LS + l] : tw[b * LS + (l - LS)];
            wid[j] = w;
            val[j] = (mask[b * L + l] > 0) && (w >= 0);
        }
        int pw = -2; bool pv = false;
        if (base > 0) {
            const int l = base - 1;
            pw = (l < LS) ? sw[b * LS + l] : tw[b * LS + (l - LS)];
            pv = (mask[b * L + l] > 0) && (pw >= 0);
        }
        int loc[8]; int c = 0;
        #pragma unroll
        for (int j = 0; j < 8; ++j) {
            const int nr = (val[j] && (wid[j] != pw || !pv)) ? 1 : 0;
            c += nr; loc[j] = c; pw = wid[j]; pv = val[j];
        }
        int inc = c;
        #pragma unroll
        for (int off = 1; off < 64; off <<= 1) {
            const int v = __shfl_up(inc, off);
            if (lane >= off) inc += v;
        }
        const int excl = inc - c;
        #pragma unroll
        for (int j = 0; j < 8; ++j) {
            const int rid = excl + loc[j] - 1;
            const int sg  = (val[j] && rid < NW) ? rid : NW;  // NW = dropped
            sseg[base + j] = sg;
            atomicAdd(&cnt[sg], 1.0f);
        }
    }

    // --- all 16 waves: both dots for this block's 64 tokens (4 per wave) ---
    {
        const float4* s4 = reinterpret_cast<const float4*>(Wp);
        const float4* g4 = reinterpret_cast<const float4*>(Wp + H);
        float4 wsv[3], wtv[3];
        #pragma unroll
        for (int k = 0; k < 3; ++k) {
            wsv[k] = s4[lane + 64 * k];
            wtv[k] = g4[lane + 64 * k];
        }
        #pragma unroll
        for (int t = 0; t < 4; ++t) {
            const int tl = wv * 4 + t;                       // 0..63
            const size_t tg = (size_t)b * L + s * 64 + tl;
            const float4* t4 = reinterpret_cast<const float4*>(tok + tg * H);
            float as = 0.f, at = 0.f;
            #pragma unroll
            for (int k = 0; k < 3; ++k) {
                const float4 a = t4[lane + 64 * k];
                as += a.x * wsv[k].x + a.y * wsv[k].y + a.z * wsv[k].z + a.w * wsv[k].w;
                at += a.x * wtv[k].x + a.y * wtv[k].y + a.z * wtv[k].z + a.w * wtv[k].w;
            }
            #pragma unroll
            for (int off = 32; off; off >>= 1) {
                as += __shfl_xor(as, off);
                at += __shfl_xor(at, off);
            }
            if (lane == 0) dv[tl] = make_float2(as, at);
        }
    }
    __syncthreads();

    // --- accumulate selected dot into private per-segment partials ---
    if (tid < 64) {
        const int sg = sseg[s * 64 + tid];
        if (sg < NW) {
            const float2 d = dv[tid];
            atomicAdd(&part[sg], (sg < S) ? d.x : d.y);
        }
    }
    __syncthreads();

    if (tid < NW) psum[g * NW + tid] = part[tid];
    __threadfence();

    cg::this_grid().sync();

    // --- reduce partials, divide by counts (cnt persists in LDS) ---
    if (tid < NW) {
        float acc = 0.f;
        #pragma unroll
        for (int k = 0; k < 8; ++k) acc += psum[(b * 8 + k) * NW + tid];
        pooled[tid] = acc / fmaxf(cnt[tid], 1.f);
    }
    __syncthreads();

    // --- write rows [s*16, s*16+16) of logits[b] ---
    if (tid < 512) {
        const float b0 = bias[0];
        const int r = s * 16 + (tid >> 5);
        const int c = (tid & 31) * 4;
        const float si = pooled[r] + b0;
        float4 v;
        v.x = si + pooled[S + c + 0];
        v.y = si + pooled[S + c + 1];
        v.z = si + pooled[S + c + 2];
        v.w = si + pooled[S + c + 3];
        *reinterpret_cast<float4*>(out + (size_t)b * S * 128 + r * 128 + c) = v;
    }
}

extern "C" void kernel_launch(void* const* d_in, const int* in_sizes, int n_in,
                              void* d_out, int out_size, void* d_ws, size_t ws_size,
                              hipStream_t stream) {
    const float* tok  = (const float*)d_in[0];   // (B, L, H) f32
    const int*   mask = (const int*)  d_in[1];   // (B, L)
    const int*   sw   = (const int*)  d_in[2];   // (B, LS)
    const int*   tw   = (const int*)  d_in[3];   // (B, LS)
    const float* W    = (const float*)d_in[4];   // (2H, 1)
    const float* bias = (const float*)d_in[5];   // (1,)
    float*       out  = (float*)d_out;           // (B, S, T)
    float*       psum = (float*)d_ws;            // 64 * NW floats

    void* args[] = { (void*)&tok, (void*)&mask, (void*)&sw, (void*)&tw,
                     (void*)&W, (void*)&bias, (void*)&out, (void*)&psum };
    hipLaunchCooperativeKernel(reinterpret_cast<void*>(fused_kernel),
                               dim3(64), dim3(1024), args, 0, stream);
}

// Round 4
// 14.309 us; speedup vs baseline: 3.6771x; 3.6771x over previous
//
#include <hip/hip_runtime.h>
#include <hip/hip_bf16.h>

// Problem constants (fixed by the reference module)
constexpr int B  = 8;
constexpr int LS = 256;            // L_SRC == L_TGT
constexpr int L  = 512;            // L_SRC + L_TGT
constexpr int H  = 768;
constexpr int S  = 128;            // N_SRC_WORDS
constexpr int NW = 256;            // S + T (pooled words used)

// ---------------------------------------------------------------------------
// Kernel A: 256 blocks x 256 threads; each wave computes BOTH dots for 4
// consecutive tokens, with the two weight vectors register-cached (reused 4x).
// Writes float2 per token.
// ---------------------------------------------------------------------------
__global__ __launch_bounds__(256) void dot2_kernel(
    const float* __restrict__ tok, const float* __restrict__ Wp,
    float2* __restrict__ dvals)
{
    const int lane = threadIdx.x & 63;
    const int wv   = threadIdx.x >> 6;
    const int t0   = (blockIdx.x * 4 + wv) * 4;     // first of 4 tokens

    const float4* s4 = reinterpret_cast<const float4*>(Wp);
    const float4* g4 = reinterpret_cast<const float4*>(Wp + H);
    float4 wsv[3], wtv[3];
    #pragma unroll
    for (int k = 0; k < 3; ++k) {
        wsv[k] = s4[lane + 64 * k];
        wtv[k] = g4[lane + 64 * k];
    }

    #pragma unroll
    for (int t = 0; t < 4; ++t) {
        const float4* t4 = reinterpret_cast<const float4*>(tok + (size_t)(t0 + t) * H);
        float as = 0.f, at = 0.f;
        #pragma unroll
        for (int k = 0; k < 3; ++k) {
            const float4 a = t4[lane + 64 * k];
            as += a.x * wsv[k].x + a.y * wsv[k].y + a.z * wsv[k].z + a.w * wsv[k].w;
            at += a.x * wtv[k].x + a.y * wtv[k].y + a.z * wtv[k].z + a.w * wtv[k].w;
        }
        #pragma unroll
        for (int off = 32; off; off >>= 1) {
            as += __shfl_xor(as, off);
            at += __shfl_xor(at, off);
        }
        if (lane == 0) dvals[t0 + t] = make_float2(as, at);
    }
}

// ---------------------------------------------------------------------------
// Kernel B: 64 blocks x 256 threads; block g=(b,s) redundantly computes the
// full pooled vector for batch b (scan + LDS reduction over 512 L2-hot dv
// entries), then writes rows [s*16, s*16+16) of the 128x128 logits.
// ---------------------------------------------------------------------------
__global__ __launch_bounds__(256) void finalize_kernel(
    const int* __restrict__ mask, const int* __restrict__ sw,
    const int* __restrict__ tw, const float2* __restrict__ dvals,
    const float* __restrict__ bias, float* __restrict__ out)
{
    const int g   = blockIdx.x;         // 0..63
    const int b   = g >> 3;
    const int s   = g & 7;
    const int tid = threadIdx.x;

    __shared__ int   sseg[L];
    __shared__ float lsum[NW + 1];
    __shared__ float lcnt[NW + 1];
    __shared__ float pooled[NW];

    if (tid < NW + 1) { lsum[tid] = 0.f; lcnt[tid] = 0.f; }
    __syncthreads();

    if (tid < 64) {                     // wave 0: run-segmentation scan
        const int lane = tid;
        const int base = lane * 8;
        int wid[8]; bool val[8];
        #pragma unroll
        for (int j = 0; j < 8; ++j) {
            const int l = base + j;
            const int w = (l < LS) ? sw[b * LS + l] : tw[b * LS + (l - LS)];
            wid[j] = w;
            val[j] = (mask[b * L + l] > 0) && (w >= 0);
        }
        int pw = -2; bool pv = false;
        if (base > 0) {
            const int l = base - 1;
            pw = (l < LS) ? sw[b * LS + l] : tw[b * LS + (l - LS)];
            pv = (mask[b * L + l] > 0) && (pw >= 0);
        }
        int loc[8]; int c = 0;
        #pragma unroll
        for (int j = 0; j < 8; ++j) {
            const int nr = (val[j] && (wid[j] != pw || !pv)) ? 1 : 0;
            c += nr; loc[j] = c; pw = wid[j]; pv = val[j];
        }
        int inc = c;
        #pragma unroll
        for (int off = 1; off < 64; off <<= 1) {
            const int v = __shfl_up(inc, off);
            if (lane >= off) inc += v;
        }
        const int excl = inc - c;
        #pragma unroll
        for (int j = 0; j < 8; ++j) {
            const int rid = excl + loc[j] - 1;
            const int sg  = (val[j] && rid < NW) ? rid : NW;   // NW = dropped
            sseg[base + j] = sg;
            atomicAdd(&lcnt[sg], 1.0f);
        }
    }
    __syncthreads();

    // accumulate selected dots: 256 threads x 2 tokens
    #pragma unroll
    for (int r = 0; r < 2; ++r) {
        const int tl = tid + r * 256;
        const int sg = sseg[tl];
        if (sg < NW) {
            const float2 d = dvals[b * L + tl];
            atomicAdd(&lsum[sg], (sg < S) ? d.x : d.y);
        }
    }
    __syncthreads();

    if (tid < NW) pooled[tid] = lsum[tid] / fmaxf(lcnt[tid], 1.f);
    __syncthreads();

    // write rows [s*16, s*16+16): 256 threads x 2 float4
    const float b0 = bias[0];
    const int r = s * 16 + (tid >> 4);          // 16 rows, 16 threads/row
    const int c = (tid & 15) * 8;               // 8 floats per thread
    const float si = pooled[r] + b0;

    float4* o = reinterpret_cast<float4*>(out + (size_t)b * S * 128 + r * 128 + c);
    #pragma unroll
    for (int j = 0; j < 8; j += 4) {
        float4 v;
        v.x = si + pooled[S + c + j + 0];
        v.y = si + pooled[S + c + j + 1];
        v.z = si + pooled[S + c + j + 2];
        v.w = si + pooled[S + c + j + 3];
        o[j >> 2] = v;
    }
}

extern "C" void kernel_launch(void* const* d_in, const int* in_sizes, int n_in,
                              void* d_out, int out_size, void* d_ws, size_t ws_size,
                              hipStream_t stream) {
    const float* tok  = (const float*)d_in[0];   // (B, L, H) f32
    const int*   mask = (const int*)  d_in[1];   // (B, L)
    const int*   sw   = (const int*)  d_in[2];   // (B, LS)
    const int*   tw   = (const int*)  d_in[3];   // (B, LS)
    const float* W    = (const float*)d_in[4];   // (2H, 1)
    const float* bias = (const float*)d_in[5];   // (1,)
    float*       out  = (float*)d_out;           // (B, S, T)

    float2* dvals = (float2*)d_ws;               // B * L float2

    dot2_kernel<<<256, 256, 0, stream>>>(tok, W, dvals);
    finalize_kernel<<<64, 256, 0, stream>>>(mask, sw, tw, dvals, bias, out);
}